// Round 6
// baseline (957.158 us; speedup 1.0000x reference)
//
#include <hip/hip_runtime.h>

#define NGF 256     // dst-regions (span = ceil(N/256) <= 512)
#define BAE 8192    // edges per bucketA block (runs avg ~32 edges = 1 cache line)
#define BAVPT 32    // BAE/256
#define CSTR 64     // colsum element stride (256B) -> spread across L2 slices

typedef float    f2 __attribute__((ext_vector_type(2)));
typedef float    f4 __attribute__((ext_vector_type(4)));
typedef float    f8 __attribute__((ext_vector_type(8)));
typedef _Float16 h8 __attribute__((ext_vector_type(8)));

__device__ __forceinline__ unsigned f2key(float x){
  unsigned b = __float_as_uint(x);
  return (b & 0x80000000u) ? ~b : (b | 0x80000000u);
}
__device__ __forceinline__ float key2f(unsigned k){
  return (k & 0x80000000u) ? __uint_as_float(k ^ 0x80000000u) : __uint_as_float(~k);
}

// fp8 e4m3 HW decode: 4 bytes -> 4 floats
__device__ __forceinline__ f4 dec4(unsigned w){
  f2 a = __builtin_amdgcn_cvt_pk_f32_fp8((int)w, false);
  f2 b = __builtin_amdgcn_cvt_pk_f32_fp8((int)w, true);
  f4 r; r[0]=a[0]; r[1]=a[1]; r[2]=b[0]; r[3]=b[1];
  return r;
}
__device__ __forceinline__ f8 dec8(uint2 w){
  f4 lo = dec4(w.x), hi = dec4(w.y);
  f8 r;
  r[0]=lo[0]; r[1]=lo[1]; r[2]=lo[2]; r[3]=lo[3];
  r[4]=hi[0]; r[5]=hi[1]; r[6]=hi[2]; r[7]=hi[3];
  return r;
}

// ---------------- CSR build v4: zero per-edge global atomics; 8192-edge bucket
//  blocks + transposed run-descriptor matrix + WAVE-PER-RUN fill (lane-parallel
//  edges, 8 waves/block: hides the load->LDS-atomic latency that bound fill4). ----------------
// pack: val = (dl<<17)|src  (dl < 512, src < 131072); meta = (gf<<13)|rank (rank < 8192)

__global__ __launch_bounds__(256) void k_bucketA(const int* __restrict__ ei,
    int* __restrict__ bucket, int* __restrict__ lbasemat,
    int E, int n, int span, unsigned magic){
  __shared__ int lcnt[NGF];
  __shared__ int lbase[NGF+1];
  __shared__ int sStage[BAE];
  __shared__ int sScan[256];
  int tid = threadIdx.x;
  lcnt[tid] = 0;
  __syncthreads();
  int base = blockIdx.x*BAE;
  int val[BAVPT], meta[BAVPT];
  #pragma unroll
  for (int i=0;i<BAVPT;i++){
    int e = base + i*256 + tid;
    meta[i] = -1;
    val[i] = 0;
    if (e < E){
      int d = ei[E + e];
      int s = ei[e];
      if ((unsigned)d < (unsigned)n && (unsigned)s < (unsigned)n){
        int gf = (int)__umulhi((unsigned)d, magic);   // d/span exact for d < 2^17
        int dl = d - gf*span;
        val[i] = (dl << 17) | s;
        int rank = atomicAdd(&lcnt[gf], 1);           // LDS atomic only
        meta[i] = (gf << 13) | rank;
      }
    }
  }
  __syncthreads();
  int v = lcnt[tid];
  sScan[tid] = v;
  __syncthreads();
  for (int o=1;o<256;o<<=1){
    int t = (tid>=o) ? sScan[tid-o] : 0;
    __syncthreads();
    if (tid>=o) sScan[tid] += t;
    __syncthreads();
  }
  lbase[tid] = sScan[tid] - v;
  if (tid == 255) lbase[NGF] = sScan[255];
  __syncthreads();
  #pragma unroll
  for (int i=0;i<BAVPT;i++){
    if (meta[i] >= 0){
      int gf   = meta[i] >> 13;
      int rank = meta[i] & 0x1FFF;
      sStage[lbase[gf] + rank] = val[i];
    }
  }
  int* row = lbasemat + (size_t)blockIdx.x*(NGF+1);
  row[tid] = lbase[tid];
  if (tid == 0) row[NGF] = lbase[NGF];
  __syncthreads();
  int* bp = bucket + (size_t)blockIdx.x*BAE;
  #pragma unroll
  for (int i=0;i<BAE/1024;i++){
    int idx = i*256 + tid;
    ((int4*)bp)[idx] = ((const int4*)sStage)[idx];   // slots beyond count: garbage, never read
  }
}

// transpose lbasemat[nb][NGF+1] -> lbT[NGF+1][nbp] so fill/rtot read runs contiguously
__global__ __launch_bounds__(1024) void k_transp(const int* __restrict__ in,
    int* __restrict__ out, int nb, int nbp){
  __shared__ int t[32][33];
  int bx = blockIdx.x*32, by = blockIdx.y*32;
  int tx = threadIdx.x, ty = threadIdx.y;
  int b = bx + ty;
  int g = by + tx;
  if (b < nb && g < NGF+1) t[ty][tx] = in[(size_t)b*(NGF+1) + g];
  __syncthreads();
  int g2 = by + ty;
  int b2 = bx + tx;
  if (g2 < NGF+1 && b2 < nb) out[(size_t)g2*nbp + b2] = t[tx][ty];
}

__global__ __launch_bounds__(256) void k_rtot(const int* __restrict__ lbT,
                                              int* __restrict__ rt, int nb, int nbp){
  __shared__ int red[256];
  int gf = blockIdx.x, tid = threadIdx.x;
  const int* lo = lbT + (size_t)gf*nbp;
  const int* hi = lo + nbp;
  int s = 0;
  for (int b=tid; b<nb; b+=256) s += hi[b] - lo[b];
  red[tid] = s;
  __syncthreads();
  for (int o=128;o>0;o>>=1){
    if (tid < o) red[tid] += red[tid+o];
    __syncthreads();
  }
  if (tid == 0) rt[gf] = red[0];
}

__global__ void k_rscan(const int* __restrict__ rt, int* __restrict__ rbase,
                        int* __restrict__ offsN){
  __shared__ int sc[256];
  int tid = threadIdx.x;
  int v = rt[tid];
  sc[tid] = v;
  __syncthreads();
  for (int o=1;o<256;o<<=1){
    int t = (tid>=o) ? sc[tid-o] : 0;
    __syncthreads();
    if (tid>=o) sc[tid] += t;
    __syncthreads();
  }
  rbase[tid] = sc[tid] - v;
  if (tid == 255){ rbase[NGF] = sc[255]; offsN[0] = sc[255]; }
}

// wave-per-run fill: a wave's 64 lanes read a run's edges coalesced (1 line for
// the avg 32-edge run) and LDS-atomic in parallel; 8 waves/block hide latency.
__global__ __launch_bounds__(512) void k_fill5(const int* __restrict__ bucket,
    const int* __restrict__ lbT, const int* __restrict__ rbase,
    int* __restrict__ csr, int* __restrict__ offs, float* __restrict__ invdeg,
    int n, int span, int nb, int nbp){
  __shared__ int sHist[512];
  __shared__ int sCur[512];
  __shared__ int sScan[512];
  int gf = blockIdx.x, tid = threadIdx.x;
  int wv = tid >> 6, lane = tid & 63;
  int rb = rbase[gf];
  const int* rowLo = lbT + (size_t)gf*nbp;
  const int* rowHi = rowLo + nbp;
  sHist[tid] = 0;
  __syncthreads();
  // pass 1: wave-per-run histogram
  for (int b = wv; b < nb; b += 8){
    int lo = rowLo[b], hi = rowHi[b];
    const int* bp = bucket + (size_t)b*BAE;
    for (int i = lo + lane; i < hi; i += 64)
      atomicAdd(&sHist[((unsigned)bp[i]) >> 17], 1);
  }
  __syncthreads();
  // exclusive scan over span (<= 512) with 512 threads
  int v = (tid < span) ? sHist[tid] : 0;
  sScan[tid] = v;
  __syncthreads();
  for (int o=1;o<512;o<<=1){
    int t = (tid>=o) ? sScan[tid-o] : 0;
    __syncthreads();
    if (tid>=o) sScan[tid] += t;
    __syncthreads();
  }
  sCur[tid] = sScan[tid] - v;
  __syncthreads();
  if (tid < span){
    int node = gf*span + tid;
    if (node < n){
      int deg = sHist[tid];
      offs[node]   = rb + sCur[tid];
      invdeg[node] = (deg > 0) ? 1.0f/(float)deg : 0.0f;  // 0 marks isolated node
    }
  }
  __syncthreads();
  // pass 2: wave-per-run place (csr writes land in region's ~50KB L2-resident window)
  for (int b = wv; b < nb; b += 8){
    int lo = rowLo[b], hi = rowHi[b];
    const int* bp = bucket + (size_t)b*BAE;
    for (int i = lo + lane; i < hi; i += 64){
      int u = bp[i];
      int pos = atomicAdd(&sCur[((unsigned)u) >> 17], 1);
      csr[rb + pos] = u & 0x1FFFF;
    }
  }
}

// ---------------- proj_in: gather x[4] + (avg@A + x@B) + row softmax -> fp8 (base 0) ----------------

__global__ __launch_bounds__(256) void k_in(const float* __restrict__ x, unsigned char* __restrict__ uout,
    const int* __restrict__ offs, const int* __restrict__ csr, const float* __restrict__ invdeg,
    const float* __restrict__ A, const float* __restrict__ B, int n){
  __shared__ float sA[128], sB[128];
  int tid = threadIdx.x;
  if (tid < 128){ sA[tid]=A[tid]; sB[tid]=B[tid]; }
  __syncthreads();
  int node = blockIdx.x*256 + tid;
  if (node >= n) return;
  float4 s = {0,0,0,0};
  int b0=offs[node], e0=offs[node+1];
  for (int k=b0;k<e0;k++){
    int sid = csr[k];
    float4 v = ((const float4*)x)[sid];
    s.x+=v.x; s.y+=v.y; s.z+=v.z; s.w+=v.w;
  }
  float idg = invdeg[node];
  s.x*=idg; s.y*=idg; s.z*=idg; s.w*=idg;
  float4 xr = ((const float4*)x)[node];
  float z[32];
  #pragma unroll
  for (int j=0;j<32;j++){
    z[j] = s.x*sA[j] + s.y*sA[32+j] + s.z*sA[64+j] + s.w*sA[96+j]
         + xr.x*sB[j] + xr.y*sB[32+j] + xr.z*sB[64+j] + xr.w*sB[96+j];
  }
  float m = z[0];
  #pragma unroll
  for (int j=1;j<32;j++) m = fmaxf(m,z[j]);
  float sum=0.0f;
  #pragma unroll
  for (int j=0;j<32;j++){ z[j]=expf(z[j]-m); sum+=z[j]; }
  float r = 1.0f/sum;
  unsigned pk[8];
  #pragma unroll
  for (int q=0;q<8;q++){
    int w0 = __builtin_amdgcn_cvt_pk_fp8_f32(z[4*q]*r,   z[4*q+1]*r, 0,  false);
    w0     = __builtin_amdgcn_cvt_pk_fp8_f32(z[4*q+2]*r, z[4*q+3]*r, w0, true);
    pk[q] = (unsigned)w0;
  }
  uint4* op = (uint4*)(uout + (size_t)node*32);
  op[0] = make_uint4(pk[0],pk[1],pk[2],pk[3]);
  op[1] = make_uint4(pk[4],pk[5],pk[6],pk[7]);
}

// ---------------- conv round (MFMA, fp8 state): PROVEN gather form. wave = 16 nodes.
//  Structural floor: one random 32B row-request per edge ~ 50us/round. ----------------

__global__ __launch_bounds__(256) void k_conv(
    const unsigned char* __restrict__ uin, unsigned char* __restrict__ uout,
    const int* __restrict__ offs, const int* __restrict__ csr,
    const float* __restrict__ invdeg,
    const float* __restrict__ Wa, const float* __restrict__ Wb,
    const float* __restrict__ cs_prev, float Rscale, float base,
    float* __restrict__ cs_next, int n){
  __shared__ float sWa[1024], sWb[1024];
  __shared__ float sCol[32];
  __shared__ unsigned char sU[64][32];
  int tid = threadIdx.x;
  float rcf = 1.0f;
  if (cs_prev) rcf = 131072.0f / ((float)n + cs_prev[(tid>>3)*CSTR]);  // rho = 2^17/colsum
  ((f4*)sWa)[tid] = ((const f4*)Wa)[tid] * rcf;
  ((f4*)sWb)[tid] = ((const f4*)Wb)[tid] * rcf;
  if (tid < 32) sCol[tid] = 0.0f;
  __syncthreads();

  int lane = tid & 63;
  int wv   = tid >> 6;
  int q    = lane >> 4;         // k-chunk (A) / row-quad (C)
  int c    = lane & 15;         // gather node (A's m) / output column (B's n, C's col)
  int tile = blockIdx.x*64 + wv*16;
  int node = tile + c;
  bool gv = node < n;

  h8 waLo, waHi, wbLo, wbHi;
  #pragma unroll
  for (int j=0;j<8;j++){
    int k = q*8 + j;
    waLo[j] = (_Float16)sWa[k*32 + c];
    waHi[j] = (_Float16)sWa[k*32 + c + 16];
    wbLo[j] = (_Float16)sWb[k*32 + c];
    wbHi[j] = (_Float16)sWb[k*32 + c + 16];
  }

  f8 a0 = {0,0,0,0,0,0,0,0}, a1 = {0,0,0,0,0,0,0,0};
  f8 a2 = {0,0,0,0,0,0,0,0}, a3 = {0,0,0,0,0,0,0,0};
  int b0 = gv ? offs[node]   : 0;
  int e0 = gv ? offs[node+1] : 0;
  const uint2* ub = (const uint2*)uin;
  int k = b0;
  for (; k+8<=e0; k+=8){
    int s0=csr[k],   s1=csr[k+1], s2=csr[k+2], s3=csr[k+3];
    int s4=csr[k+4], s5=csr[k+5], s6=csr[k+6], s7=csr[k+7];
    uint2 v0 = ub[(size_t)s0*4 + q];
    uint2 v1 = ub[(size_t)s1*4 + q];
    uint2 v2 = ub[(size_t)s2*4 + q];
    uint2 v3 = ub[(size_t)s3*4 + q];
    uint2 v4 = ub[(size_t)s4*4 + q];
    uint2 v5 = ub[(size_t)s5*4 + q];
    uint2 v6 = ub[(size_t)s6*4 + q];
    uint2 v7 = ub[(size_t)s7*4 + q];
    a0 += dec8(v0); a1 += dec8(v1); a2 += dec8(v2); a3 += dec8(v3);
    a0 += dec8(v4); a1 += dec8(v5); a2 += dec8(v6); a3 += dec8(v7);
  }
  for (; k<e0; k++) a0 += dec8(ub[(size_t)csr[k]*4 + q]);
  a0 = (a0 + a1) + (a2 + a3);
  float idg = gv ? invdeg[node] : 0.0f;
  float bavg = (idg != 0.0f) ? base : 0.0f;   // ref: isolated node -> avg = 0
  a0 = a0*idg + bavg;
  h8 afrag = __builtin_convertvector(a0, h8);
  f8 od = {0,0,0,0,0,0,0,0};
  if (gv) od = dec8(ub[(size_t)node*4 + q]) + base;
  h8 ofrag = __builtin_convertvector(od, h8);

  f4 z1 = {0,0,0,0}, z2 = {0,0,0,0};
  z1 = __builtin_amdgcn_mfma_f32_16x16x32_f16(ofrag, wbLo, z1, 0, 0, 0);
  z1 = __builtin_amdgcn_mfma_f32_16x16x32_f16(afrag, waLo, z1, 0, 0, 0);
  z2 = __builtin_amdgcn_mfma_f32_16x16x32_f16(ofrag, wbHi, z2, 0, 0, 0);
  z2 = __builtin_amdgcn_mfma_f32_16x16x32_f16(afrag, waHi, z2, 0, 0, 0);
  z1 *= Rscale; z2 *= Rscale;

  f4 mx, sm;
  #pragma unroll
  for (int r=0;r<4;r++) mx[r] = fmaxf(z1[r], z2[r]);
  #pragma unroll
  for (int s=1;s<16;s<<=1){
    #pragma unroll
    for (int r=0;r<4;r++) mx[r] = fmaxf(mx[r], __shfl_xor(mx[r], s));
  }
  #pragma unroll
  for (int r=0;r<4;r++){
    z1[r] = expf(z1[r]-mx[r]);
    z2[r] = expf(z2[r]-mx[r]);
    sm[r] = z1[r] + z2[r];
  }
  #pragma unroll
  for (int s=1;s<16;s<<=1){
    #pragma unroll
    for (int r=0;r<4;r++) sm[r] += __shfl_xor(sm[r], s);
  }
  float cs1 = 0.0f, cs2 = 0.0f;
  #pragma unroll
  for (int r=0;r<4;r++){
    float rs = 1.0f/sm[r];
    float v1 = expf(z1[r]*rs) - 1.0f;   // store v = u - 1, v in [0, 1.72] (fp8-friendly)
    float v2 = expf(z2[r]*rs) - 1.0f;
    int p1 = __builtin_amdgcn_cvt_pk_fp8_f32(v1, v1, 0, false);
    int p2 = __builtin_amdgcn_cvt_pk_fp8_f32(v2, v2, 0, false);
    f2 d1 = __builtin_amdgcn_cvt_pk_f32_fp8(p1, false);
    f2 d2 = __builtin_amdgcn_cvt_pk_f32_fp8(p2, false);
    int lrow = wv*16 + q*4 + r;
    sU[lrow][c]      = (unsigned char)(p1 & 0xff);
    sU[lrow][c + 16] = (unsigned char)(p2 & 0xff);
    if (tile + q*4 + r < n){
      cs1 += d1[0];                 // colsum consistent with stored (rounded) v
      cs2 += d2[0];
    }
  }
  cs1 += __shfl_xor(cs1, 16); cs1 += __shfl_xor(cs1, 32);
  cs2 += __shfl_xor(cs2, 16); cs2 += __shfl_xor(cs2, 32);
  if (lane < 16){
    atomicAdd(&sCol[c],      cs1);
    atomicAdd(&sCol[c + 16], cs2);
  }
  __syncthreads();
  if (tid < 32) atomicAdd(&cs_next[tid*CSTR], sCol[tid]);
  int row = tid >> 2;
  int jj  = tid & 3;
  int gnode = blockIdx.x*64 + row;
  if (gnode < n){
    uint2 val = *(const uint2*)&sU[row][jj*8];
    *(uint2*)(uout + (size_t)gnode*32 + jj*8) = val;
  }
}

// ---------------- output layer: z = (1+v)@ (W/colsum) + b ----------------

__global__ __launch_bounds__(256) void k_out1(const unsigned char* __restrict__ u, const float* __restrict__ W,
    const float* __restrict__ bptr, const float* __restrict__ cs_last,
    float* __restrict__ z, unsigned* __restrict__ zmaxkey, int n){
  __shared__ float ws[32];
  __shared__ float red[256];
  int tid = threadIdx.x;
  if (tid < 32) ws[tid] = W[tid] * (1.0f / ((float)n + cs_last[tid*CSTR]));
  __syncthreads();
  float sws = 0.0f;
  #pragma unroll
  for (int j=0;j<32;j++) sws += ws[j];
  int node = blockIdx.x*256 + tid;
  float zz = -3.0e38f;
  if (node < n){
    float acc = bptr[0] + sws;
    const uint4* ur = (const uint4*)(u + (size_t)node*32);
    uint4 w0 = ur[0], w1 = ur[1];
    unsigned wd[8] = {w0.x,w0.y,w0.z,w0.w,w1.x,w1.y,w1.z,w1.w};
    #pragma unroll
    for (int q=0;q<8;q++){
      f4 a = dec4(wd[q]);
      f4 w = ((const f4*)ws)[q];
      acc += a[0]*w[0] + a[1]*w[1] + a[2]*w[2] + a[3]*w[3];
    }
    z[node]=acc; zz=acc;
  }
  red[tid]=zz; __syncthreads();
  for (int s=128;s>0;s>>=1){
    if (tid<s) red[tid]=fmaxf(red[tid],red[tid+s]);
    __syncthreads();
  }
  if (tid==0) atomicMax(zmaxkey, f2key(red[0]));
}

__global__ __launch_bounds__(256) void k_out2(const float* __restrict__ z, const unsigned* __restrict__ zmaxkey,
                                              float* __restrict__ zsum, int n){
  __shared__ float red[256];
  int tid = threadIdx.x;
  int node = blockIdx.x*256 + tid;
  float zmax = key2f(*zmaxkey);
  float v = (node<n) ? expf(z[node]-zmax) : 0.0f;
  red[tid]=v; __syncthreads();
  for (int s=128;s>0;s>>=1){
    if (tid<s) red[tid]+=red[tid+s];
    __syncthreads();
  }
  if (tid==0) atomicAdd(zsum, red[0]);
}

__global__ __launch_bounds__(256) void k_out3(const float* __restrict__ z, const unsigned* __restrict__ zmaxkey,
                                              const float* __restrict__ zsum, float* __restrict__ out, int n){
  int node = blockIdx.x*256 + threadIdx.x;
  if (node < n){
    float zmax = key2f(*zmaxkey);
    out[node] = expf(z[node]-zmax) / (*zsum);
  }
}

// ---------------- host launcher ----------------

extern "C" void kernel_launch(void* const* d_in, const int* in_sizes, int n_in,
                              void* d_out, int out_size, void* d_ws, size_t ws_size,
                              hipStream_t stream) {
  const float* x      = (const float*)d_in[0];
  const int*   ei     = (const int*)d_in[1];
  const float* A_in   = (const float*)d_in[2];
  const float* B_in   = (const float*)d_in[3];
  const float* A_conv = (const float*)d_in[4];
  const float* B_conv = (const float*)d_in[5];
  const float* W_out  = (const float*)d_in[6];
  const float* b_out  = (const float*)d_in[7];
  const int N = in_sizes[0] / 4;
  const int E = in_sizes[1] / 2;
  const int NROUNDS = 16;

  char* w = (char*)d_ws;
  size_t o = 0;
  auto alloc = [&](size_t bytes)->char* {
    char* p = w + o;
    o = (o + bytes + 15) & ~(size_t)15;
    return p;
  };
  // ---- zero-init control region (one memset) ----
  float*    colsum  = (float*)   alloc((size_t)NROUNDS*32*CSTR*4);
  unsigned* zmaxkey = (unsigned*)alloc(4);
  float*    zsum    = (float*)   alloc(4);
  size_t ctrl_bytes = o;
  // ---- rest (fully written before read; no zeroing needed) ----
  int    nb      = (E + BAE-1) / BAE;          // 8192-edge blocks
  int    span    = (N + NGF - 1) / NGF;        // <= 512 for N <= 131072
  int*   offs    = (int*)  alloc((size_t)(N+1)*4);
  float* invdeg  = (float*)alloc((size_t)N*4);
  int*   csr     = (int*)  alloc((size_t)E*4);
  int*   bucket  = (int*)  alloc((size_t)nb*BAE*4);
  int*   lbasemat= (int*)  alloc((size_t)nb*(NGF+1)*4);
  int*   lbT     = (int*)  alloc((size_t)(NGF+1)*nb*4);
  int*   rt      = (int*)  alloc((size_t)NGF*4);
  int*   rbase   = (int*)  alloc((size_t)(NGF+1)*4);
  unsigned char* uA = (unsigned char*)alloc((size_t)N*32);
  unsigned char* uB = (unsigned char*)alloc((size_t)N*32);
  float* zbuf    = (float*)alloc((size_t)N*4);
  (void)ws_size; (void)n_in; (void)out_size;

  hipMemsetAsync(d_ws, 0, ctrl_bytes, stream);

  unsigned magic = (unsigned)((((unsigned long long)1 << 32) + (unsigned long long)span - 1)
                              / (unsigned long long)span);
  int gridN = (N + 255) / 256;
  int gridC = (N + 63) / 64;

  // CSR build: no per-edge global atomics anywhere; wave-per-run fill
  k_bucketA<<<nb, 256, 0, stream>>>(ei, bucket, lbasemat, E, N, span, magic);
  {
    dim3 tb(32,32);
    dim3 tg((nb + 31)/32, (NGF+1 + 31)/32);
    k_transp<<<tg, tb, 0, stream>>>(lbasemat, lbT, nb, nb);
  }
  k_rtot <<<NGF, 256, 0, stream>>>(lbT, rt, nb, nb);
  k_rscan<<<1, 256, 0, stream>>>(rt, rbase, offs + N);
  k_fill5<<<NGF, 512, 0, stream>>>(bucket, lbT, rbase, csr, offs, invdeg, N, span, nb, nb);

  // proj_in -> p stored fp8 (base 0)
  k_in<<<gridN, 256, 0, stream>>>(x, uA, offs, csr, invdeg, A_in, B_in, N);

  // 16 conv rounds (proven gather form)
  const float R17 = 1.0f/131072.0f;
  for (int r = 0; r < NROUNDS; r++){
    const float* Wa = A_conv + (size_t)r*32*32;
    const float* Wb = B_conv + (size_t)r*32*32;
    const float* cs_prev = (r == 0) ? nullptr : (colsum + (size_t)(r-1)*32*CSTR);
    float*       cs_next = colsum + (size_t)r*32*CSTR;
    float        Rs      = (r == 0) ? 1.0f : R17;
    float        base    = (r == 0) ? 0.0f : 1.0f;
    const unsigned char* ui = (r & 1) ? uB : uA;
    unsigned char*       uo = (r & 1) ? uA : uB;
    k_conv<<<gridC, 256, 0, stream>>>(ui, uo, offs, csr, invdeg, Wa, Wb, cs_prev, Rs, base, cs_next, N);
  }

  // output layer (colsum_16 = n + sum(v); folded into W_out)
  k_out1<<<gridN, 256, 0, stream>>>(uA, W_out, b_out, colsum + (size_t)(NROUNDS-1)*32*CSTR, zbuf, zmaxkey, N);
  k_out2<<<gridN, 256, 0, stream>>>(zbuf, zmaxkey, zsum, N);
  k_out3<<<gridN, 256, 0, stream>>>(zbuf, zmaxkey, zsum, (float*)d_out, N);
}

// Round 7
// 920.315 us; speedup vs baseline: 1.0400x; 1.0400x over previous
//
#include <hip/hip_runtime.h>

#define NGF 256     // dst-regions (span = ceil(N/256) <= 512)
#define BAE 8192    // edges per bucketA block (runs avg ~32 edges = 1 cache line)
#define BAVPT 32    // BAE/256
#define CSTR 64     // colsum element stride (256B) -> spread across L2 slices
#define ECAP 13056  // LDS edge-stage capacity (region mean 12500, +5 sigma; overflow guarded)
#define FT 1024     // fill threads
#define FW 16       // fill waves

typedef float    f2 __attribute__((ext_vector_type(2)));
typedef float    f4 __attribute__((ext_vector_type(4)));
typedef float    f8 __attribute__((ext_vector_type(8)));
typedef _Float16 h8 __attribute__((ext_vector_type(8)));

__device__ __forceinline__ unsigned f2key(float x){
  unsigned b = __float_as_uint(x);
  return (b & 0x80000000u) ? ~b : (b | 0x80000000u);
}
__device__ __forceinline__ float key2f(unsigned k){
  return (k & 0x80000000u) ? __uint_as_float(k ^ 0x80000000u) : __uint_as_float(~k);
}

// fp8 e4m3 HW decode: 4 bytes -> 4 floats
__device__ __forceinline__ f4 dec4(unsigned w){
  f2 a = __builtin_amdgcn_cvt_pk_f32_fp8((int)w, false);
  f2 b = __builtin_amdgcn_cvt_pk_f32_fp8((int)w, true);
  f4 r; r[0]=a[0]; r[1]=a[1]; r[2]=b[0]; r[3]=b[1];
  return r;
}
__device__ __forceinline__ f8 dec8(uint2 w){
  f4 lo = dec4(w.x), hi = dec4(w.y);
  f8 r;
  r[0]=lo[0]; r[1]=lo[1]; r[2]=lo[2]; r[3]=lo[3];
  r[4]=hi[0]; r[5]=hi[1]; r[6]=hi[2]; r[7]=hi[3];
  return r;
}

// ---------------- CSR build v5: zero per-edge global atomics. 8192-edge bucket
//  blocks + transposed run-descriptor matrix + SINGLE-PASS fill: stage region's
//  edges in LDS (compacted via run-length prefix) while histogramming; placement
//  reads LDS. Halves the serial latency walk that bound fill4/fill5. ----------------
// pack: val = (dl<<17)|src  (dl < 512, src < 131072); meta = (gf<<13)|rank (rank < 8192)

__global__ __launch_bounds__(256) void k_bucketA(const int* __restrict__ ei,
    int* __restrict__ bucket, int* __restrict__ lbasemat,
    int E, int n, int span, unsigned magic){
  __shared__ int lcnt[NGF];
  __shared__ int lbase[NGF+1];
  __shared__ int sStage[BAE];
  __shared__ int sScan[256];
  int tid = threadIdx.x;
  lcnt[tid] = 0;
  __syncthreads();
  int base = blockIdx.x*BAE;
  int val[BAVPT], meta[BAVPT];
  #pragma unroll
  for (int i=0;i<BAVPT;i++){
    int e = base + i*256 + tid;
    meta[i] = -1;
    val[i] = 0;
    if (e < E){
      int d = ei[E + e];
      int s = ei[e];
      if ((unsigned)d < (unsigned)n && (unsigned)s < (unsigned)n){
        int gf = (int)__umulhi((unsigned)d, magic);   // d/span exact for d < 2^17
        int dl = d - gf*span;
        val[i] = (dl << 17) | s;
        int rank = atomicAdd(&lcnt[gf], 1);           // LDS atomic only
        meta[i] = (gf << 13) | rank;
      }
    }
  }
  __syncthreads();
  int v = lcnt[tid];
  sScan[tid] = v;
  __syncthreads();
  for (int o=1;o<256;o<<=1){
    int t = (tid>=o) ? sScan[tid-o] : 0;
    __syncthreads();
    if (tid>=o) sScan[tid] += t;
    __syncthreads();
  }
  lbase[tid] = sScan[tid] - v;
  if (tid == 255) lbase[NGF] = sScan[255];
  __syncthreads();
  #pragma unroll
  for (int i=0;i<BAVPT;i++){
    if (meta[i] >= 0){
      int gf   = meta[i] >> 13;
      int rank = meta[i] & 0x1FFF;
      sStage[lbase[gf] + rank] = val[i];
    }
  }
  int* row = lbasemat + (size_t)blockIdx.x*(NGF+1);
  row[tid] = lbase[tid];
  if (tid == 0) row[NGF] = lbase[NGF];
  __syncthreads();
  int* bp = bucket + (size_t)blockIdx.x*BAE;
  #pragma unroll
  for (int i=0;i<BAE/1024;i++){
    int idx = i*256 + tid;
    ((int4*)bp)[idx] = ((const int4*)sStage)[idx];   // slots beyond count: garbage, never read
  }
}

// transpose lbasemat[nb][NGF+1] -> lbT[NGF+1][nbp] so fill/rtot read runs contiguously
__global__ __launch_bounds__(1024) void k_transp(const int* __restrict__ in,
    int* __restrict__ out, int nb, int nbp){
  __shared__ int t[32][33];
  int bx = blockIdx.x*32, by = blockIdx.y*32;
  int tx = threadIdx.x, ty = threadIdx.y;
  int b = bx + ty;
  int g = by + tx;
  if (b < nb && g < NGF+1) t[ty][tx] = in[(size_t)b*(NGF+1) + g];
  __syncthreads();
  int g2 = by + ty;
  int b2 = bx + tx;
  if (g2 < NGF+1 && b2 < nb) out[(size_t)g2*nbp + b2] = t[tx][ty];
}

__global__ __launch_bounds__(256) void k_rtot(const int* __restrict__ lbT,
                                              int* __restrict__ rt, int nb, int nbp){
  __shared__ int red[256];
  int gf = blockIdx.x, tid = threadIdx.x;
  const int* lo = lbT + (size_t)gf*nbp;
  const int* hi = lo + nbp;
  int s = 0;
  for (int b=tid; b<nb; b+=256) s += hi[b] - lo[b];
  red[tid] = s;
  __syncthreads();
  for (int o=128;o>0;o>>=1){
    if (tid < o) red[tid] += red[tid+o];
    __syncthreads();
  }
  if (tid == 0) rt[gf] = red[0];
}

__global__ void k_rscan(const int* __restrict__ rt, int* __restrict__ rbase,
                        int* __restrict__ offsN){
  __shared__ int sc[256];
  int tid = threadIdx.x;
  int v = rt[tid];
  sc[tid] = v;
  __syncthreads();
  for (int o=1;o<256;o<<=1){
    int t = (tid>=o) ? sc[tid-o] : 0;
    __syncthreads();
    if (tid>=o) sc[tid] += t;
    __syncthreads();
  }
  rbase[tid] = sc[tid] - v;
  if (tid == 255){ rbase[NGF] = sc[255]; offsN[0] = sc[255]; }
}

// single-pass fill: wave-per-run stages edges into compacted LDS + histograms;
// placement reads LDS (no second global latency walk). nb <= 512 (one run/thread
// for the prefix). Overflow beyond ECAP handled by a rare global walk.
__global__ __launch_bounds__(FT) void k_fill6(const int* __restrict__ bucket,
    const int* __restrict__ lbT, const int* __restrict__ rbase,
    int* __restrict__ csr, int* __restrict__ offs, float* __restrict__ invdeg,
    int n, int span, int nb, int nbp){
  __shared__ int sEdges[ECAP];   // 52224 B
  __shared__ int sHist[512];     // 2048
  __shared__ int sCur[512];      // 2048
  __shared__ int sScan[FT];      // 4096
  __shared__ int sPre[512];      // 2048
  __shared__ int sLo[512];       // 2048  -> total 64512 B (< 64KB)
  int gf = blockIdx.x, tid = threadIdx.x;
  int wv = tid >> 6, lane = tid & 63;
  int rb = rbase[gf];
  const int* rowLo = lbT + (size_t)gf*nbp;
  const int* rowHi = rowLo + nbp;
  // run descriptors (each tid owns <=1 run; nb <= 512)
  int len = 0;
  if (tid < nb){
    int lo = rowLo[tid];
    sLo[tid] = tid*BAE + lo;
    len = rowHi[tid] - lo;
  }
  if (tid < 512) sHist[tid] = 0;
  sScan[tid] = (tid < nb) ? len : 0;
  __syncthreads();
  for (int o=1;o<FT;o<<=1){
    int t = (tid>=o) ? sScan[tid-o] : 0;
    __syncthreads();
    if (tid>=o) sScan[tid] += t;
    __syncthreads();
  }
  if (tid < nb) sPre[tid] = sScan[tid] - len;
  int total = sScan[FT-1];         // kept in register (sScan reused below)
  __syncthreads();
  // pass 1 (single global walk): stage + histogram
  for (int b = wv; b < nb; b += FW){
    int pre = sPre[b];
    int nxt = (b+1 < nb) ? sPre[b+1] : total;
    int ln  = nxt - pre;
    const int* bp = bucket + sLo[b];
    for (int i = lane; i < ln; i += 64){
      int v = bp[i];
      atomicAdd(&sHist[((unsigned)v) >> 17], 1);
      int gi = pre + i;
      if (gi < ECAP) sEdges[gi] = v;
    }
  }
  __syncthreads();
  // hist exclusive scan over span (<= 512; one node/thread)
  int hv = (tid < span) ? sHist[tid] : 0;
  sScan[tid] = hv;
  __syncthreads();
  for (int o=1;o<FT;o<<=1){
    int t = (tid>=o) ? sScan[tid-o] : 0;
    __syncthreads();
    if (tid>=o) sScan[tid] += t;
    __syncthreads();
  }
  if (tid < span){
    int ex = sScan[tid] - hv;
    sCur[tid] = ex;
    int node = gf*span + tid;
    if (node < n){
      offs[node]   = rb + ex;
      invdeg[node] = (hv > 0) ? 1.0f/(float)hv : 0.0f;  // 0 marks isolated node
    }
  }
  __syncthreads();
  // placement from LDS
  int tcap = (total < ECAP) ? total : ECAP;
  for (int i = tid; i < tcap; i += FT){
    int v = sEdges[i];
    int pos = atomicAdd(&sCur[((unsigned)v) >> 17], 1);
    csr[rb + pos] = v & 0x1FFFF;
  }
  // overflow (rare): place un-staged edges straight from global
  if (total > ECAP){
    for (int b = wv; b < nb; b += FW){
      int pre = sPre[b];
      int nxt = (b+1 < nb) ? sPre[b+1] : total;
      if (nxt <= ECAP) continue;
      int st = (pre >= ECAP) ? 0 : (ECAP - pre);
      int ln = nxt - pre;
      const int* bp = bucket + sLo[b];
      for (int i = st + lane; i < ln; i += 64){
        int v = bp[i];
        int pos = atomicAdd(&sCur[((unsigned)v) >> 17], 1);
        csr[rb + pos] = v & 0x1FFFF;
      }
    }
  }
}

// ---------------- proj_in: gather x[4] + (avg@A + x@B) + row softmax -> fp8 (base 0) ----------------

__global__ __launch_bounds__(256) void k_in(const float* __restrict__ x, unsigned char* __restrict__ uout,
    const int* __restrict__ offs, const int* __restrict__ csr, const float* __restrict__ invdeg,
    const float* __restrict__ A, const float* __restrict__ B, int n){
  __shared__ float sA[128], sB[128];
  int tid = threadIdx.x;
  if (tid < 128){ sA[tid]=A[tid]; sB[tid]=B[tid]; }
  __syncthreads();
  int node = blockIdx.x*256 + tid;
  if (node >= n) return;
  float4 s = {0,0,0,0};
  int b0=offs[node], e0=offs[node+1];
  for (int k=b0;k<e0;k++){
    int sid = csr[k];
    float4 v = ((const float4*)x)[sid];
    s.x+=v.x; s.y+=v.y; s.z+=v.z; s.w+=v.w;
  }
  float idg = invdeg[node];
  s.x*=idg; s.y*=idg; s.z*=idg; s.w*=idg;
  float4 xr = ((const float4*)x)[node];
  float z[32];
  #pragma unroll
  for (int j=0;j<32;j++){
    z[j] = s.x*sA[j] + s.y*sA[32+j] + s.z*sA[64+j] + s.w*sA[96+j]
         + xr.x*sB[j] + xr.y*sB[32+j] + xr.z*sB[64+j] + xr.w*sB[96+j];
  }
  float m = z[0];
  #pragma unroll
  for (int j=1;j<32;j++) m = fmaxf(m,z[j]);
  float sum=0.0f;
  #pragma unroll
  for (int j=0;j<32;j++){ z[j]=expf(z[j]-m); sum+=z[j]; }
  float r = 1.0f/sum;
  unsigned pk[8];
  #pragma unroll
  for (int q=0;q<8;q++){
    int w0 = __builtin_amdgcn_cvt_pk_fp8_f32(z[4*q]*r,   z[4*q+1]*r, 0,  false);
    w0     = __builtin_amdgcn_cvt_pk_fp8_f32(z[4*q+2]*r, z[4*q+3]*r, w0, true);
    pk[q] = (unsigned)w0;
  }
  uint4* op = (uint4*)(uout + (size_t)node*32);
  op[0] = make_uint4(pk[0],pk[1],pk[2],pk[3]);
  op[1] = make_uint4(pk[4],pk[5],pk[6],pk[7]);
}

// ---------------- conv round (MFMA, fp8 state): PROVEN gather form. wave = 16 nodes.
//  Structural floor: one random 32B row-request per edge ~ 50us/round. ----------------

__global__ __launch_bounds__(256) void k_conv(
    const unsigned char* __restrict__ uin, unsigned char* __restrict__ uout,
    const int* __restrict__ offs, const int* __restrict__ csr,
    const float* __restrict__ invdeg,
    const float* __restrict__ Wa, const float* __restrict__ Wb,
    const float* __restrict__ cs_prev, float Rscale, float base,
    float* __restrict__ cs_next, int n){
  __shared__ float sWa[1024], sWb[1024];
  __shared__ float sCol[32];
  __shared__ unsigned char sU[64][32];
  int tid = threadIdx.x;
  float rcf = 1.0f;
  if (cs_prev) rcf = 131072.0f / ((float)n + cs_prev[(tid>>3)*CSTR]);  // rho = 2^17/colsum
  ((f4*)sWa)[tid] = ((const f4*)Wa)[tid] * rcf;
  ((f4*)sWb)[tid] = ((const f4*)Wb)[tid] * rcf;
  if (tid < 32) sCol[tid] = 0.0f;
  __syncthreads();

  int lane = tid & 63;
  int wv   = tid >> 6;
  int q    = lane >> 4;         // k-chunk (A) / row-quad (C)
  int c    = lane & 15;         // gather node (A's m) / output column (B's n, C's col)
  int tile = blockIdx.x*64 + wv*16;
  int node = tile + c;
  bool gv = node < n;

  h8 waLo, waHi, wbLo, wbHi;
  #pragma unroll
  for (int j=0;j<8;j++){
    int k = q*8 + j;
    waLo[j] = (_Float16)sWa[k*32 + c];
    waHi[j] = (_Float16)sWa[k*32 + c + 16];
    wbLo[j] = (_Float16)sWb[k*32 + c];
    wbHi[j] = (_Float16)sWb[k*32 + c + 16];
  }

  f8 a0 = {0,0,0,0,0,0,0,0}, a1 = {0,0,0,0,0,0,0,0};
  f8 a2 = {0,0,0,0,0,0,0,0}, a3 = {0,0,0,0,0,0,0,0};
  int b0 = gv ? offs[node]   : 0;
  int e0 = gv ? offs[node+1] : 0;
  const uint2* ub = (const uint2*)uin;
  int k = b0;
  for (; k+8<=e0; k+=8){
    int s0=csr[k],   s1=csr[k+1], s2=csr[k+2], s3=csr[k+3];
    int s4=csr[k+4], s5=csr[k+5], s6=csr[k+6], s7=csr[k+7];
    uint2 v0 = ub[(size_t)s0*4 + q];
    uint2 v1 = ub[(size_t)s1*4 + q];
    uint2 v2 = ub[(size_t)s2*4 + q];
    uint2 v3 = ub[(size_t)s3*4 + q];
    uint2 v4 = ub[(size_t)s4*4 + q];
    uint2 v5 = ub[(size_t)s5*4 + q];
    uint2 v6 = ub[(size_t)s6*4 + q];
    uint2 v7 = ub[(size_t)s7*4 + q];
    a0 += dec8(v0); a1 += dec8(v1); a2 += dec8(v2); a3 += dec8(v3);
    a0 += dec8(v4); a1 += dec8(v5); a2 += dec8(v6); a3 += dec8(v7);
  }
  for (; k<e0; k++) a0 += dec8(ub[(size_t)csr[k]*4 + q]);
  a0 = (a0 + a1) + (a2 + a3);
  float idg = gv ? invdeg[node] : 0.0f;
  float bavg = (idg != 0.0f) ? base : 0.0f;   // ref: isolated node -> avg = 0
  a0 = a0*idg + bavg;
  h8 afrag = __builtin_convertvector(a0, h8);
  f8 od = {0,0,0,0,0,0,0,0};
  if (gv) od = dec8(ub[(size_t)node*4 + q]) + base;
  h8 ofrag = __builtin_convertvector(od, h8);

  f4 z1 = {0,0,0,0}, z2 = {0,0,0,0};
  z1 = __builtin_amdgcn_mfma_f32_16x16x32_f16(ofrag, wbLo, z1, 0, 0, 0);
  z1 = __builtin_amdgcn_mfma_f32_16x16x32_f16(afrag, waLo, z1, 0, 0, 0);
  z2 = __builtin_amdgcn_mfma_f32_16x16x32_f16(ofrag, wbHi, z2, 0, 0, 0);
  z2 = __builtin_amdgcn_mfma_f32_16x16x32_f16(afrag, waHi, z2, 0, 0, 0);
  z1 *= Rscale; z2 *= Rscale;

  f4 mx, sm;
  #pragma unroll
  for (int r=0;r<4;r++) mx[r] = fmaxf(z1[r], z2[r]);
  #pragma unroll
  for (int s=1;s<16;s<<=1){
    #pragma unroll
    for (int r=0;r<4;r++) mx[r] = fmaxf(mx[r], __shfl_xor(mx[r], s));
  }
  #pragma unroll
  for (int r=0;r<4;r++){
    z1[r] = expf(z1[r]-mx[r]);
    z2[r] = expf(z2[r]-mx[r]);
    sm[r] = z1[r] + z2[r];
  }
  #pragma unroll
  for (int s=1;s<16;s<<=1){
    #pragma unroll
    for (int r=0;r<4;r++) sm[r] += __shfl_xor(sm[r], s);
  }
  float cs1 = 0.0f, cs2 = 0.0f;
  #pragma unroll
  for (int r=0;r<4;r++){
    float rs = 1.0f/sm[r];
    float v1 = expf(z1[r]*rs) - 1.0f;   // store v = u - 1, v in [0, 1.72] (fp8-friendly)
    float v2 = expf(z2[r]*rs) - 1.0f;
    int p1 = __builtin_amdgcn_cvt_pk_fp8_f32(v1, v1, 0, false);
    int p2 = __builtin_amdgcn_cvt_pk_fp8_f32(v2, v2, 0, false);
    f2 d1 = __builtin_amdgcn_cvt_pk_f32_fp8(p1, false);
    f2 d2 = __builtin_amdgcn_cvt_pk_f32_fp8(p2, false);
    int lrow = wv*16 + q*4 + r;
    sU[lrow][c]      = (unsigned char)(p1 & 0xff);
    sU[lrow][c + 16] = (unsigned char)(p2 & 0xff);
    if (tile + q*4 + r < n){
      cs1 += d1[0];                 // colsum consistent with stored (rounded) v
      cs2 += d2[0];
    }
  }
  cs1 += __shfl_xor(cs1, 16); cs1 += __shfl_xor(cs1, 32);
  cs2 += __shfl_xor(cs2, 16); cs2 += __shfl_xor(cs2, 32);
  if (lane < 16){
    atomicAdd(&sCol[c],      cs1);
    atomicAdd(&sCol[c + 16], cs2);
  }
  __syncthreads();
  if (tid < 32) atomicAdd(&cs_next[tid*CSTR], sCol[tid]);
  int row = tid >> 2;
  int jj  = tid & 3;
  int gnode = blockIdx.x*64 + row;
  if (gnode < n){
    uint2 val = *(const uint2*)&sU[row][jj*8];
    *(uint2*)(uout + (size_t)gnode*32 + jj*8) = val;
  }
}

// ---------------- output layer: z = (1+v)@ (W/colsum) + b ----------------

__global__ __launch_bounds__(256) void k_out1(const unsigned char* __restrict__ u, const float* __restrict__ W,
    const float* __restrict__ bptr, const float* __restrict__ cs_last,
    float* __restrict__ z, unsigned* __restrict__ zmaxkey, int n){
  __shared__ float ws[32];
  __shared__ float red[256];
  int tid = threadIdx.x;
  if (tid < 32) ws[tid] = W[tid] * (1.0f / ((float)n + cs_last[tid*CSTR]));
  __syncthreads();
  float sws = 0.0f;
  #pragma unroll
  for (int j=0;j<32;j++) sws += ws[j];
  int node = blockIdx.x*256 + tid;
  float zz = -3.0e38f;
  if (node < n){
    float acc = bptr[0] + sws;
    const uint4* ur = (const uint4*)(u + (size_t)node*32);
    uint4 w0 = ur[0], w1 = ur[1];
    unsigned wd[8] = {w0.x,w0.y,w0.z,w0.w,w1.x,w1.y,w1.z,w1.w};
    #pragma unroll
    for (int q=0;q<8;q++){
      f4 a = dec4(wd[q]);
      f4 w = ((const f4*)ws)[q];
      acc += a[0]*w[0] + a[1]*w[1] + a[2]*w[2] + a[3]*w[3];
    }
    z[node]=acc; zz=acc;
  }
  red[tid]=zz; __syncthreads();
  for (int s=128;s>0;s>>=1){
    if (tid<s) red[tid]=fmaxf(red[tid],red[tid+s]);
    __syncthreads();
  }
  if (tid==0) atomicMax(zmaxkey, f2key(red[0]));
}

__global__ __launch_bounds__(256) void k_out2(const float* __restrict__ z, const unsigned* __restrict__ zmaxkey,
                                              float* __restrict__ zsum, int n){
  __shared__ float red[256];
  int tid = threadIdx.x;
  int node = blockIdx.x*256 + tid;
  float zmax = key2f(*zmaxkey);
  float v = (node<n) ? expf(z[node]-zmax) : 0.0f;
  red[tid]=v; __syncthreads();
  for (int s=128;s>0;s>>=1){
    if (tid<s) red[tid]+=red[tid+s];
    __syncthreads();
  }
  if (tid==0) atomicAdd(zsum, red[0]);
}

__global__ __launch_bounds__(256) void k_out3(const float* __restrict__ z, const unsigned* __restrict__ zmaxkey,
                                              const float* __restrict__ zsum, float* __restrict__ out, int n){
  int node = blockIdx.x*256 + threadIdx.x;
  if (node < n){
    float zmax = key2f(*zmaxkey);
    out[node] = expf(z[node]-zmax) / (*zsum);
  }
}

// ---------------- host launcher ----------------

extern "C" void kernel_launch(void* const* d_in, const int* in_sizes, int n_in,
                              void* d_out, int out_size, void* d_ws, size_t ws_size,
                              hipStream_t stream) {
  const float* x      = (const float*)d_in[0];
  const int*   ei     = (const int*)d_in[1];
  const float* A_in   = (const float*)d_in[2];
  const float* B_in   = (const float*)d_in[3];
  const float* A_conv = (const float*)d_in[4];
  const float* B_conv = (const float*)d_in[5];
  const float* W_out  = (const float*)d_in[6];
  const float* b_out  = (const float*)d_in[7];
  const int N = in_sizes[0] / 4;
  const int E = in_sizes[1] / 2;
  const int NROUNDS = 16;

  char* w = (char*)d_ws;
  size_t o = 0;
  auto alloc = [&](size_t bytes)->char* {
    char* p = w + o;
    o = (o + bytes + 15) & ~(size_t)15;
    return p;
  };
  // ---- zero-init control region (one memset) ----
  float*    colsum  = (float*)   alloc((size_t)NROUNDS*32*CSTR*4);
  unsigned* zmaxkey = (unsigned*)alloc(4);
  float*    zsum    = (float*)   alloc(4);
  size_t ctrl_bytes = o;
  // ---- rest (fully written before read; no zeroing needed) ----
  int    nb      = (E + BAE-1) / BAE;          // 8192-edge blocks (<= 512)
  int    span    = (N + NGF - 1) / NGF;        // <= 512 for N <= 131072
  int*   offs    = (int*)  alloc((size_t)(N+1)*4);
  float* invdeg  = (float*)alloc((size_t)N*4);
  int*   csr     = (int*)  alloc((size_t)E*4);
  int*   bucket  = (int*)  alloc((size_t)nb*BAE*4);
  int*   lbasemat= (int*)  alloc((size_t)nb*(NGF+1)*4);
  int*   lbT     = (int*)  alloc((size_t)(NGF+1)*nb*4);
  int*   rt      = (int*)  alloc((size_t)NGF*4);
  int*   rbase   = (int*)  alloc((size_t)(NGF+1)*4);
  unsigned char* uA = (unsigned char*)alloc((size_t)N*32);
  unsigned char* uB = (unsigned char*)alloc((size_t)N*32);
  float* zbuf    = (float*)alloc((size_t)N*4);
  (void)ws_size; (void)n_in; (void)out_size;

  hipMemsetAsync(d_ws, 0, ctrl_bytes, stream);

  unsigned magic = (unsigned)((((unsigned long long)1 << 32) + (unsigned long long)span - 1)
                              / (unsigned long long)span);
  int gridN = (N + 255) / 256;
  int gridC = (N + 63) / 64;

  // CSR build: no per-edge global atomics anywhere; single-pass LDS-staged fill
  k_bucketA<<<nb, 256, 0, stream>>>(ei, bucket, lbasemat, E, N, span, magic);
  {
    dim3 tb(32,32);
    dim3 tg((nb + 31)/32, (NGF+1 + 31)/32);
    k_transp<<<tg, tb, 0, stream>>>(lbasemat, lbT, nb, nb);
  }
  k_rtot <<<NGF, 256, 0, stream>>>(lbT, rt, nb, nb);
  k_rscan<<<1, 256, 0, stream>>>(rt, rbase, offs + N);
  k_fill6<<<NGF, FT, 0, stream>>>(bucket, lbT, rbase, csr, offs, invdeg, N, span, nb, nb);

  // proj_in -> p stored fp8 (base 0)
  k_in<<<gridN, 256, 0, stream>>>(x, uA, offs, csr, invdeg, A_in, B_in, N);

  // 16 conv rounds (proven gather form)
  const float R17 = 1.0f/131072.0f;
  for (int r = 0; r < NROUNDS; r++){
    const float* Wa = A_conv + (size_t)r*32*32;
    const float* Wb = B_conv + (size_t)r*32*32;
    const float* cs_prev = (r == 0) ? nullptr : (colsum + (size_t)(r-1)*32*CSTR);
    float*       cs_next = colsum + (size_t)r*32*CSTR;
    float        Rs      = (r == 0) ? 1.0f : R17;
    float        base    = (r == 0) ? 0.0f : 1.0f;
    const unsigned char* ui = (r & 1) ? uB : uA;
    unsigned char*       uo = (r & 1) ? uA : uB;
    k_conv<<<gridC, 256, 0, stream>>>(ui, uo, offs, csr, invdeg, Wa, Wb, cs_prev, Rs, base, cs_next, N);
  }

  // output layer (colsum_16 = n + sum(v); folded into W_out)
  k_out1<<<gridN, 256, 0, stream>>>(uA, W_out, b_out, colsum + (size_t)(NROUNDS-1)*32*CSTR, zbuf, zmaxkey, N);
  k_out2<<<gridN, 256, 0, stream>>>(zbuf, zmaxkey, zsum, N);
  k_out3<<<gridN, 256, 0, stream>>>(zbuf, zmaxkey, zsum, (float*)d_out, N);
}

// Round 8
// 893.031 us; speedup vs baseline: 1.0718x; 1.0306x over previous
//
#include <hip/hip_runtime.h>

#define NGF 256     // dst-regions (span = ceil(N/256) <= 512)
#define BAE 8192    // edges per bucketA block (runs avg ~32 edges = 1 cache line)
#define BAVPT 32    // BAE/256
#define CSTR 64     // colsum element stride (256B) -> spread across L2 slices
#define ECAP 13056  // LDS edge-stage capacity (region mean 12500, +5 sigma; overflow guarded)
#define FT 1024     // fill threads
#define FW 16       // fill waves

typedef float    f2 __attribute__((ext_vector_type(2)));
typedef float    f4 __attribute__((ext_vector_type(4)));
typedef float    f8 __attribute__((ext_vector_type(8)));
typedef _Float16 h8 __attribute__((ext_vector_type(8)));

__device__ __forceinline__ unsigned f2key(float x){
  unsigned b = __float_as_uint(x);
  return (b & 0x80000000u) ? ~b : (b | 0x80000000u);
}
__device__ __forceinline__ float key2f(unsigned k){
  return (k & 0x80000000u) ? __uint_as_float(k ^ 0x80000000u) : __uint_as_float(~k);
}

// fp8 e4m3 HW decode: 4 bytes -> 4 floats
__device__ __forceinline__ f4 dec4(unsigned w){
  f2 a = __builtin_amdgcn_cvt_pk_f32_fp8((int)w, false);
  f2 b = __builtin_amdgcn_cvt_pk_f32_fp8((int)w, true);
  f4 r; r[0]=a[0]; r[1]=a[1]; r[2]=b[0]; r[3]=b[1];
  return r;
}
__device__ __forceinline__ f8 dec8(uint2 w){
  f4 lo = dec4(w.x), hi = dec4(w.y);
  f8 r;
  r[0]=lo[0]; r[1]=lo[1]; r[2]=lo[2]; r[3]=lo[3];
  r[4]=hi[0]; r[5]=hi[1]; r[6]=hi[2]; r[7]=hi[3];
  return r;
}

// ---------------- CSR build v5 (R19, measured): zero per-edge global atomics;
//  single-pass LDS-staged fill. ----------------
// pack: val = (dl<<17)|src  (dl < 512, src < 131072); meta = (gf<<13)|rank (rank < 8192)

__global__ __launch_bounds__(256) void k_bucketA(const int* __restrict__ ei,
    int* __restrict__ bucket, int* __restrict__ lbasemat,
    int E, int n, int span, unsigned magic){
  __shared__ int lcnt[NGF];
  __shared__ int lbase[NGF+1];
  __shared__ int sStage[BAE];
  __shared__ int sScan[256];
  int tid = threadIdx.x;
  lcnt[tid] = 0;
  __syncthreads();
  int base = blockIdx.x*BAE;
  int val[BAVPT], meta[BAVPT];
  #pragma unroll
  for (int i=0;i<BAVPT;i++){
    int e = base + i*256 + tid;
    meta[i] = -1;
    val[i] = 0;
    if (e < E){
      int d = ei[E + e];
      int s = ei[e];
      if ((unsigned)d < (unsigned)n && (unsigned)s < (unsigned)n){
        int gf = (int)__umulhi((unsigned)d, magic);   // d/span exact for d < 2^17
        int dl = d - gf*span;
        val[i] = (dl << 17) | s;
        int rank = atomicAdd(&lcnt[gf], 1);           // LDS atomic only
        meta[i] = (gf << 13) | rank;
      }
    }
  }
  __syncthreads();
  int v = lcnt[tid];
  sScan[tid] = v;
  __syncthreads();
  for (int o=1;o<256;o<<=1){
    int t = (tid>=o) ? sScan[tid-o] : 0;
    __syncthreads();
    if (tid>=o) sScan[tid] += t;
    __syncthreads();
  }
  lbase[tid] = sScan[tid] - v;
  if (tid == 255) lbase[NGF] = sScan[255];
  __syncthreads();
  #pragma unroll
  for (int i=0;i<BAVPT;i++){
    if (meta[i] >= 0){
      int gf   = meta[i] >> 13;
      int rank = meta[i] & 0x1FFF;
      sStage[lbase[gf] + rank] = val[i];
    }
  }
  int* row = lbasemat + (size_t)blockIdx.x*(NGF+1);
  row[tid] = lbase[tid];
  if (tid == 0) row[NGF] = lbase[NGF];
  __syncthreads();
  int* bp = bucket + (size_t)blockIdx.x*BAE;
  #pragma unroll
  for (int i=0;i<BAE/1024;i++){
    int idx = i*256 + tid;
    ((int4*)bp)[idx] = ((const int4*)sStage)[idx];   // slots beyond count: garbage, never read
  }
}

// transpose lbasemat[nb][NGF+1] -> lbT[NGF+1][nbp] so fill/rtot read runs contiguously
__global__ __launch_bounds__(1024) void k_transp(const int* __restrict__ in,
    int* __restrict__ out, int nb, int nbp){
  __shared__ int t[32][33];
  int bx = blockIdx.x*32, by = blockIdx.y*32;
  int tx = threadIdx.x, ty = threadIdx.y;
  int b = bx + ty;
  int g = by + tx;
  if (b < nb && g < NGF+1) t[ty][tx] = in[(size_t)b*(NGF+1) + g];
  __syncthreads();
  int g2 = by + ty;
  int b2 = bx + tx;
  if (g2 < NGF+1 && b2 < nb) out[(size_t)g2*nbp + b2] = t[tx][ty];
}

__global__ __launch_bounds__(256) void k_rtot(const int* __restrict__ lbT,
                                              int* __restrict__ rt, int nb, int nbp){
  __shared__ int red[256];
  int gf = blockIdx.x, tid = threadIdx.x;
  const int* lo = lbT + (size_t)gf*nbp;
  const int* hi = lo + nbp;
  int s = 0;
  for (int b=tid; b<nb; b+=256) s += hi[b] - lo[b];
  red[tid] = s;
  __syncthreads();
  for (int o=128;o>0;o>>=1){
    if (tid < o) red[tid] += red[tid+o];
    __syncthreads();
  }
  if (tid == 0) rt[gf] = red[0];
}

__global__ void k_rscan(const int* __restrict__ rt, int* __restrict__ rbase,
                        int* __restrict__ offsN){
  __shared__ int sc[256];
  int tid = threadIdx.x;
  int v = rt[tid];
  sc[tid] = v;
  __syncthreads();
  for (int o=1;o<256;o<<=1){
    int t = (tid>=o) ? sc[tid-o] : 0;
    __syncthreads();
    if (tid>=o) sc[tid] += t;
    __syncthreads();
  }
  rbase[tid] = sc[tid] - v;
  if (tid == 255){ rbase[NGF] = sc[255]; offsN[0] = sc[255]; }
}

// single-pass fill: wave-per-run stages edges into compacted LDS + histograms;
// placement reads LDS (no second global latency walk).
__global__ __launch_bounds__(FT) void k_fill6(const int* __restrict__ bucket,
    const int* __restrict__ lbT, const int* __restrict__ rbase,
    int* __restrict__ csr, int* __restrict__ offs, float* __restrict__ invdeg,
    int n, int span, int nb, int nbp){
  __shared__ int sEdges[ECAP];
  __shared__ int sHist[512];
  __shared__ int sCur[512];
  __shared__ int sScan[FT];
  __shared__ int sPre[512];
  __shared__ int sLo[512];
  int gf = blockIdx.x, tid = threadIdx.x;
  int wv = tid >> 6, lane = tid & 63;
  int rb = rbase[gf];
  const int* rowLo = lbT + (size_t)gf*nbp;
  const int* rowHi = rowLo + nbp;
  int len = 0;
  if (tid < nb){
    int lo = rowLo[tid];
    sLo[tid] = tid*BAE + lo;
    len = rowHi[tid] - lo;
  }
  if (tid < 512) sHist[tid] = 0;
  sScan[tid] = (tid < nb) ? len : 0;
  __syncthreads();
  for (int o=1;o<FT;o<<=1){
    int t = (tid>=o) ? sScan[tid-o] : 0;
    __syncthreads();
    if (tid>=o) sScan[tid] += t;
    __syncthreads();
  }
  if (tid < nb) sPre[tid] = sScan[tid] - len;
  int total = sScan[FT-1];
  __syncthreads();
  for (int b = wv; b < nb; b += FW){
    int pre = sPre[b];
    int nxt = (b+1 < nb) ? sPre[b+1] : total;
    int ln  = nxt - pre;
    const int* bp = bucket + sLo[b];
    for (int i = lane; i < ln; i += 64){
      int v = bp[i];
      atomicAdd(&sHist[((unsigned)v) >> 17], 1);
      int gi = pre + i;
      if (gi < ECAP) sEdges[gi] = v;
    }
  }
  __syncthreads();
  int hv = (tid < span) ? sHist[tid] : 0;
  sScan[tid] = hv;
  __syncthreads();
  for (int o=1;o<FT;o<<=1){
    int t = (tid>=o) ? sScan[tid-o] : 0;
    __syncthreads();
    if (tid>=o) sScan[tid] += t;
    __syncthreads();
  }
  if (tid < span){
    int ex = sScan[tid] - hv;
    sCur[tid] = ex;
    int node = gf*span + tid;
    if (node < n){
      offs[node]   = rb + ex;
      invdeg[node] = (hv > 0) ? 1.0f/(float)hv : 0.0f;  // 0 marks isolated node
    }
  }
  __syncthreads();
  int tcap = (total < ECAP) ? total : ECAP;
  for (int i = tid; i < tcap; i += FT){
    int v = sEdges[i];
    int pos = atomicAdd(&sCur[((unsigned)v) >> 17], 1);
    csr[rb + pos] = v & 0x1FFFF;
  }
  if (total > ECAP){
    for (int b = wv; b < nb; b += FW){
      int pre = sPre[b];
      int nxt = (b+1 < nb) ? sPre[b+1] : total;
      if (nxt <= ECAP) continue;
      int st = (pre >= ECAP) ? 0 : (ECAP - pre);
      int ln = nxt - pre;
      const int* bp = bucket + sLo[b];
      for (int i = st + lane; i < ln; i += 64){
        int v = bp[i];
        int pos = atomicAdd(&sCur[((unsigned)v) >> 17], 1);
        csr[rb + pos] = v & 0x1FFFF;
      }
    }
  }
}

// ---------------- proj_in: gather x[4] + (avg@A + x@B) + row softmax -> fp8 (base 0) ----------------

__global__ __launch_bounds__(256) void k_in(const float* __restrict__ x, unsigned char* __restrict__ uout,
    const int* __restrict__ offs, const int* __restrict__ csr, const float* __restrict__ invdeg,
    const float* __restrict__ A, const float* __restrict__ B, int n){
  __shared__ float sA[128], sB[128];
  int tid = threadIdx.x;
  if (tid < 128){ sA[tid]=A[tid]; sB[tid]=B[tid]; }
  __syncthreads();
  int node = blockIdx.x*256 + tid;
  if (node >= n) return;
  float4 s = {0,0,0,0};
  int b0=offs[node], e0=offs[node+1];
  for (int k=b0;k<e0;k++){
    int sid = csr[k];
    float4 v = ((const float4*)x)[sid];
    s.x+=v.x; s.y+=v.y; s.z+=v.z; s.w+=v.w;
  }
  float idg = invdeg[node];
  s.x*=idg; s.y*=idg; s.z*=idg; s.w*=idg;
  float4 xr = ((const float4*)x)[node];
  float z[32];
  #pragma unroll
  for (int j=0;j<32;j++){
    z[j] = s.x*sA[j] + s.y*sA[32+j] + s.z*sA[64+j] + s.w*sA[96+j]
         + xr.x*sB[j] + xr.y*sB[32+j] + xr.z*sB[64+j] + xr.w*sB[96+j];
  }
  float m = z[0];
  #pragma unroll
  for (int j=1;j<32;j++) m = fmaxf(m,z[j]);
  float sum=0.0f;
  #pragma unroll
  for (int j=0;j<32;j++){ z[j]=expf(z[j]-m); sum+=z[j]; }
  float r = 1.0f/sum;
  unsigned pk[8];
  #pragma unroll
  for (int q=0;q<8;q++){
    int w0 = __builtin_amdgcn_cvt_pk_fp8_f32(z[4*q]*r,   z[4*q+1]*r, 0,  false);
    w0     = __builtin_amdgcn_cvt_pk_fp8_f32(z[4*q+2]*r, z[4*q+3]*r, w0, true);
    pk[q] = (unsigned)w0;
  }
  uint4* op = (uint4*)(uout + (size_t)node*32);
  op[0] = make_uint4(pk[0],pk[1],pk[2],pk[3]);
  op[1] = make_uint4(pk[4],pk[5],pk[6],pk[7]);
}

// ---------------- conv round (MFMA, fp8 state): gather form + SOFTWARE-PIPELINED
//  index stream (R20): batch i+1's csr loads issue while batch i's gathers are in
//  flight -> exposed latency per 8-edge iter drops from (csr + gather) to
//  max(csr, gather). Self-row load hoisted above the loop. ----------------

__global__ __launch_bounds__(256) void k_conv(
    const unsigned char* __restrict__ uin, unsigned char* __restrict__ uout,
    const int* __restrict__ offs, const int* __restrict__ csr,
    const float* __restrict__ invdeg,
    const float* __restrict__ Wa, const float* __restrict__ Wb,
    const float* __restrict__ cs_prev, float Rscale, float base,
    float* __restrict__ cs_next, int n){
  __shared__ float sWa[1024], sWb[1024];
  __shared__ float sCol[32];
  __shared__ unsigned char sU[64][32];
  int tid = threadIdx.x;
  float rcf = 1.0f;
  if (cs_prev) rcf = 131072.0f / ((float)n + cs_prev[(tid>>3)*CSTR]);  // rho = 2^17/colsum
  ((f4*)sWa)[tid] = ((const f4*)Wa)[tid] * rcf;
  ((f4*)sWb)[tid] = ((const f4*)Wb)[tid] * rcf;
  if (tid < 32) sCol[tid] = 0.0f;
  __syncthreads();

  int lane = tid & 63;
  int wv   = tid >> 6;
  int q    = lane >> 4;         // k-chunk (A) / row-quad (C)
  int c    = lane & 15;         // gather node (A's m) / output column (B's n, C's col)
  int tile = blockIdx.x*64 + wv*16;
  int node = tile + c;
  bool gv = node < n;

  h8 waLo, waHi, wbLo, wbHi;
  #pragma unroll
  for (int j=0;j<8;j++){
    int k = q*8 + j;
    waLo[j] = (_Float16)sWa[k*32 + c];
    waHi[j] = (_Float16)sWa[k*32 + c + 16];
    wbLo[j] = (_Float16)sWb[k*32 + c];
    wbHi[j] = (_Float16)sWb[k*32 + c + 16];
  }

  f8 a0 = {0,0,0,0,0,0,0,0}, a1 = {0,0,0,0,0,0,0,0};
  f8 a2 = {0,0,0,0,0,0,0,0}, a3 = {0,0,0,0,0,0,0,0};
  int b0 = gv ? offs[node]   : 0;
  int e0 = gv ? offs[node+1] : 0;
  const uint2* ub = (const uint2*)uin;

  // self-row load in flight across the whole gather loop
  f8 od = {0,0,0,0,0,0,0,0};
  uint2 odw = make_uint2(0u,0u);
  if (gv) odw = ub[(size_t)node*4 + q];

  int k = b0;
  // prologue: indices for first batch
  int s0=0,s1=0,s2=0,s3=0,s4=0,s5=0,s6=0,s7=0;
  if (k+8<=e0){
    s0=csr[k];   s1=csr[k+1]; s2=csr[k+2]; s3=csr[k+3];
    s4=csr[k+4]; s5=csr[k+5]; s6=csr[k+6]; s7=csr[k+7];
  }
  for (; k+8<=e0; ){
    // issue gathers for current batch (addresses from registers)
    uint2 v0 = ub[(size_t)s0*4 + q];
    uint2 v1 = ub[(size_t)s1*4 + q];
    uint2 v2 = ub[(size_t)s2*4 + q];
    uint2 v3 = ub[(size_t)s3*4 + q];
    uint2 v4 = ub[(size_t)s4*4 + q];
    uint2 v5 = ub[(size_t)s5*4 + q];
    uint2 v6 = ub[(size_t)s6*4 + q];
    uint2 v7 = ub[(size_t)s7*4 + q];
    k += 8;
    // prefetch next batch's indices while gathers are in flight
    if (k+8<=e0){
      s0=csr[k];   s1=csr[k+1]; s2=csr[k+2]; s3=csr[k+3];
      s4=csr[k+4]; s5=csr[k+5]; s6=csr[k+6]; s7=csr[k+7];
    }
    // consume gathers (vmcnt waits leave the csr prefetch in flight)
    a0 += dec8(v0); a1 += dec8(v1); a2 += dec8(v2); a3 += dec8(v3);
    a0 += dec8(v4); a1 += dec8(v5); a2 += dec8(v6); a3 += dec8(v7);
  }
  for (; k<e0; k++) a0 += dec8(ub[(size_t)csr[k]*4 + q]);
  a0 = (a0 + a1) + (a2 + a3);
  float idg = gv ? invdeg[node] : 0.0f;
  float bavg = (idg != 0.0f) ? base : 0.0f;   // ref: isolated node -> avg = 0
  a0 = a0*idg + bavg;
  h8 afrag = __builtin_convertvector(a0, h8);
  if (gv) od = dec8(odw) + base;
  h8 ofrag = __builtin_convertvector(od, h8);

  f4 z1 = {0,0,0,0}, z2 = {0,0,0,0};
  z1 = __builtin_amdgcn_mfma_f32_16x16x32_f16(ofrag, wbLo, z1, 0, 0, 0);
  z1 = __builtin_amdgcn_mfma_f32_16x16x32_f16(afrag, waLo, z1, 0, 0, 0);
  z2 = __builtin_amdgcn_mfma_f32_16x16x32_f16(ofrag, wbHi, z2, 0, 0, 0);
  z2 = __builtin_amdgcn_mfma_f32_16x16x32_f16(afrag, waHi, z2, 0, 0, 0);
  z1 *= Rscale; z2 *= Rscale;

  f4 mx, sm;
  #pragma unroll
  for (int r=0;r<4;r++) mx[r] = fmaxf(z1[r], z2[r]);
  #pragma unroll
  for (int s=1;s<16;s<<=1){
    #pragma unroll
    for (int r=0;r<4;r++) mx[r] = fmaxf(mx[r], __shfl_xor(mx[r], s));
  }
  #pragma unroll
  for (int r=0;r<4;r++){
    z1[r] = expf(z1[r]-mx[r]);
    z2[r] = expf(z2[r]-mx[r]);
    sm[r] = z1[r] + z2[r];
  }
  #pragma unroll
  for (int s=1;s<16;s<<=1){
    #pragma unroll
    for (int r=0;r<4;r++) sm[r] += __shfl_xor(sm[r], s);
  }
  float cs1 = 0.0f, cs2 = 0.0f;
  #pragma unroll
  for (int r=0;r<4;r++){
    float rs = 1.0f/sm[r];
    float v1 = expf(z1[r]*rs) - 1.0f;   // store v = u - 1, v in [0, 1.72] (fp8-friendly)
    float v2 = expf(z2[r]*rs) - 1.0f;
    int p1 = __builtin_amdgcn_cvt_pk_fp8_f32(v1, v1, 0, false);
    int p2 = __builtin_amdgcn_cvt_pk_fp8_f32(v2, v2, 0, false);
    f2 d1 = __builtin_amdgcn_cvt_pk_f32_fp8(p1, false);
    f2 d2 = __builtin_amdgcn_cvt_pk_f32_fp8(p2, false);
    int lrow = wv*16 + q*4 + r;
    sU[lrow][c]      = (unsigned char)(p1 & 0xff);
    sU[lrow][c + 16] = (unsigned char)(p2 & 0xff);
    if (tile + q*4 + r < n){
      cs1 += d1[0];                 // colsum consistent with stored (rounded) v
      cs2 += d2[0];
    }
  }
  cs1 += __shfl_xor(cs1, 16); cs1 += __shfl_xor(cs1, 32);
  cs2 += __shfl_xor(cs2, 16); cs2 += __shfl_xor(cs2, 32);
  if (lane < 16){
    atomicAdd(&sCol[c],      cs1);
    atomicAdd(&sCol[c + 16], cs2);
  }
  __syncthreads();
  if (tid < 32) atomicAdd(&cs_next[tid*CSTR], sCol[tid]);
  int row = tid >> 2;
  int jj  = tid & 3;
  int gnode = blockIdx.x*64 + row;
  if (gnode < n){
    uint2 val = *(const uint2*)&sU[row][jj*8];
    *(uint2*)(uout + (size_t)gnode*32 + jj*8) = val;
  }
}

// ---------------- output layer: z = (1+v)@ (W/colsum) + b ----------------

__global__ __launch_bounds__(256) void k_out1(const unsigned char* __restrict__ u, const float* __restrict__ W,
    const float* __restrict__ bptr, const float* __restrict__ cs_last,
    float* __restrict__ z, unsigned* __restrict__ zmaxkey, int n){
  __shared__ float ws[32];
  __shared__ float red[256];
  int tid = threadIdx.x;
  if (tid < 32) ws[tid] = W[tid] * (1.0f / ((float)n + cs_last[tid*CSTR]));
  __syncthreads();
  float sws = 0.0f;
  #pragma unroll
  for (int j=0;j<32;j++) sws += ws[j];
  int node = blockIdx.x*256 + tid;
  float zz = -3.0e38f;
  if (node < n){
    float acc = bptr[0] + sws;
    const uint4* ur = (const uint4*)(u + (size_t)node*32);
    uint4 w0 = ur[0], w1 = ur[1];
    unsigned wd[8] = {w0.x,w0.y,w0.z,w0.w,w1.x,w1.y,w1.z,w1.w};
    #pragma unroll
    for (int q=0;q<8;q++){
      f4 a = dec4(wd[q]);
      f4 w = ((const f4*)ws)[q];
      acc += a[0]*w[0] + a[1]*w[1] + a[2]*w[2] + a[3]*w[3];
    }
    z[node]=acc; zz=acc;
  }
  red[tid]=zz; __syncthreads();
  for (int s=128;s>0;s>>=1){
    if (tid<s) red[tid]=fmaxf(red[tid],red[tid+s]);
    __syncthreads();
  }
  if (tid==0) atomicMax(zmaxkey, f2key(red[0]));
}

__global__ __launch_bounds__(256) void k_out2(const float* __restrict__ z, const unsigned* __restrict__ zmaxkey,
                                              float* __restrict__ zsum, int n){
  __shared__ float red[256];
  int tid = threadIdx.x;
  int node = blockIdx.x*256 + tid;
  float zmax = key2f(*zmaxkey);
  float v = (node<n) ? expf(z[node]-zmax) : 0.0f;
  red[tid]=v; __syncthreads();
  for (int s=128;s>0;s>>=1){
    if (tid<s) red[tid]+=red[tid+s];
    __syncthreads();
  }
  if (tid==0) atomicAdd(zsum, red[0]);
}

__global__ __launch_bounds__(256) void k_out3(const float* __restrict__ z, const unsigned* __restrict__ zmaxkey,
                                              const float* __restrict__ zsum, float* __restrict__ out, int n){
  int node = blockIdx.x*256 + threadIdx.x;
  if (node < n){
    float zmax = key2f(*zmaxkey);
    out[node] = expf(z[node]-zmax) / (*zsum);
  }
}

// ---------------- host launcher ----------------

extern "C" void kernel_launch(void* const* d_in, const int* in_sizes, int n_in,
                              void* d_out, int out_size, void* d_ws, size_t ws_size,
                              hipStream_t stream) {
  const float* x      = (const float*)d_in[0];
  const int*   ei     = (const int*)d_in[1];
  const float* A_in   = (const float*)d_in[2];
  const float* B_in   = (const float*)d_in[3];
  const float* A_conv = (const float*)d_in[4];
  const float* B_conv = (const float*)d_in[5];
  const float* W_out  = (const float*)d_in[6];
  const float* b_out  = (const float*)d_in[7];
  const int N = in_sizes[0] / 4;
  const int E = in_sizes[1] / 2;
  const int NROUNDS = 16;

  char* w = (char*)d_ws;
  size_t o = 0;
  auto alloc = [&](size_t bytes)->char* {
    char* p = w + o;
    o = (o + bytes + 15) & ~(size_t)15;
    return p;
  };
  // ---- zero-init control region (one memset) ----
  float*    colsum  = (float*)   alloc((size_t)NROUNDS*32*CSTR*4);
  unsigned* zmaxkey = (unsigned*)alloc(4);
  float*    zsum    = (float*)   alloc(4);
  size_t ctrl_bytes = o;
  // ---- rest (fully written before read; no zeroing needed) ----
  int    nb      = (E + BAE-1) / BAE;          // 8192-edge blocks (<= 512)
  int    span    = (N + NGF - 1) / NGF;        // <= 512 for N <= 131072
  int*   offs    = (int*)  alloc((size_t)(N+1)*4);
  float* invdeg  = (float*)alloc((size_t)N*4);
  int*   csr     = (int*)  alloc((size_t)E*4);
  int*   bucket  = (int*)  alloc((size_t)nb*BAE*4);
  int*   lbasemat= (int*)  alloc((size_t)nb*(NGF+1)*4);
  int*   lbT     = (int*)  alloc((size_t)(NGF+1)*nb*4);
  int*   rt      = (int*)  alloc((size_t)NGF*4);
  int*   rbase   = (int*)  alloc((size_t)(NGF+1)*4);
  unsigned char* uA = (unsigned char*)alloc((size_t)N*32);
  unsigned char* uB = (unsigned char*)alloc((size_t)N*32);
  float* zbuf    = (float*)alloc((size_t)N*4);
  (void)ws_size; (void)n_in; (void)out_size;

  hipMemsetAsync(d_ws, 0, ctrl_bytes, stream);

  unsigned magic = (unsigned)((((unsigned long long)1 << 32) + (unsigned long long)span - 1)
                              / (unsigned long long)span);
  int gridN = (N + 255) / 256;
  int gridC = (N + 63) / 64;

  // CSR build: no per-edge global atomics anywhere; single-pass LDS-staged fill
  k_bucketA<<<nb, 256, 0, stream>>>(ei, bucket, lbasemat, E, N, span, magic);
  {
    dim3 tb(32,32);
    dim3 tg((nb + 31)/32, (NGF+1 + 31)/32);
    k_transp<<<tg, tb, 0, stream>>>(lbasemat, lbT, nb, nb);
  }
  k_rtot <<<NGF, 256, 0, stream>>>(lbT, rt, nb, nb);
  k_rscan<<<1, 256, 0, stream>>>(rt, rbase, offs + N);
  k_fill6<<<NGF, FT, 0, stream>>>(bucket, lbT, rbase, csr, offs, invdeg, N, span, nb, nb);

  // proj_in -> p stored fp8 (base 0)
  k_in<<<gridN, 256, 0, stream>>>(x, uA, offs, csr, invdeg, A_in, B_in, N);

  // 16 conv rounds (pipelined gather form)
  const float R17 = 1.0f/131072.0f;
  for (int r = 0; r < NROUNDS; r++){
    const float* Wa = A_conv + (size_t)r*32*32;
    const float* Wb = B_conv + (size_t)r*32*32;
    const float* cs_prev = (r == 0) ? nullptr : (colsum + (size_t)(r-1)*32*CSTR);
    float*       cs_next = colsum + (size_t)r*32*CSTR;
    float        Rs      = (r == 0) ? 1.0f : R17;
    float        base    = (r == 0) ? 0.0f : 1.0f;
    const unsigned char* ui = (r & 1) ? uB : uA;
    unsigned char*       uo = (r & 1) ? uA : uB;
    k_conv<<<gridC, 256, 0, stream>>>(ui, uo, offs, csr, invdeg, Wa, Wb, cs_prev, Rs, base, cs_next, N);
  }

  // output layer (colsum_16 = n + sum(v); folded into W_out)
  k_out1<<<gridN, 256, 0, stream>>>(uA, W_out, b_out, colsum + (size_t)(NROUNDS-1)*32*CSTR, zbuf, zmaxkey, N);
  k_out2<<<gridN, 256, 0, stream>>>(zbuf, zmaxkey, zsum, N);
  k_out3<<<gridN, 256, 0, stream>>>(zbuf, zmaxkey, zsum, (float*)d_out, N);
}